// Round 3
// baseline (7624.742 us; speedup 1.0000x reference)
//
#include <hip/hip_runtime.h>
#include <math.h>

#define TT 8
#define NN 50000
#define HH 128
#define EE 800000

#define BM 32
#define BN 128
#define BK 32

#define M_SCALE 0
#define M_GATE  1
#define M_CAND  2
#define M_OUT   3

__device__ __forceinline__ float sigmoidf_(float x){ return 1.0f/(1.0f+__expf(-x)); }

// ---------------- CSR build ----------------

__global__ void count_kernel(const int* __restrict__ dst, int* __restrict__ counts){
  int e = blockIdx.x*256 + threadIdx.x;
  if (e < EE) atomicAdd(&counts[dst[e]], 1);
}

__global__ void scan_kernel(const int* __restrict__ counts, int* __restrict__ offs,
                            float* __restrict__ dinv){
  __shared__ int part[1024];
  const int t = threadIdx.x;
  const int per = (NN + 1023)/1024;   // 49
  int beg = t*per; int end = beg+per;
  if (end > NN) end = NN;
  if (beg > NN) beg = NN;
  int s = 0;
  for (int i=beg;i<end;i++) s += counts[i];
  part[t] = s; __syncthreads();
  for (int d=1; d<1024; d<<=1){
    int v = (t>=d) ? part[t-d] : 0;
    __syncthreads();
    part[t] += v;
    __syncthreads();
  }
  int run = part[t] - s;               // exclusive prefix of this segment
  for (int i=beg;i<end;i++){
    offs[i] = run;
    int c = counts[i];
    run += c;
    dinv[i] = rsqrtf((float)c + 1.0f); // deg includes +1 self loop
  }
  if (t==1023) offs[NN] = run;
}

__global__ void fill_kernel(const int* __restrict__ src, const int* __restrict__ dst,
                            const int* __restrict__ offs, int* __restrict__ cursor,
                            int* __restrict__ csr){
  int e = blockIdx.x*256 + threadIdx.x;
  if (e < EE){
    int d = dst[e];
    int p = atomicAdd(&cursor[d], 1);
    csr[offs[d]+p] = src[e];
  }
}

// ---------------- GCN aggregation ----------------
// out[i] = act( dinv[i] * (Ys[i] + sum_{src in in(i)} Ys[src]) + bias )
template<int RELU>
__global__ __launch_bounds__(256) void agg_kernel(
    const float* __restrict__ Ys, const int* __restrict__ csr,
    const int* __restrict__ offs, const float* __restrict__ dinv,
    const float* __restrict__ bias, float* __restrict__ out)
{
  const int node = blockIdx.x*8 + (threadIdx.x>>5);
  if (node >= NN) return;
  const int lane = threadIdx.x & 31;
  const float4* Y4 = (const float4*)Ys;
  float4 a = Y4[(size_t)node*32 + lane];   // self-loop term (pre-scaled by dinv[node])
  float acc0=a.x, acc1=a.y, acc2=a.z, acc3=a.w;
  const int b = offs[node], e = offs[node+1];
  for (int j=b;j<e;j++){
    int s = csr[j];
    float4 v = Y4[(size_t)s*32 + lane];
    acc0+=v.x; acc1+=v.y; acc2+=v.z; acc3+=v.w;
  }
  const float d = dinv[node];
  const float4 bb = *(const float4*)(bias + lane*4);
  float o0 = acc0*d + bb.x;
  float o1 = acc1*d + bb.y;
  float o2 = acc2*d + bb.z;
  float o3 = acc3*d + bb.w;
  if (RELU){ o0=fmaxf(o0,0.f); o1=fmaxf(o1,0.f); o2=fmaxf(o2,0.f); o3=fmaxf(o3,0.f); }
  *(float4*)(out + (size_t)node*HH + lane*4) = make_float4(o0,o1,o2,o3);
}

// ---------------- fused GEMM ----------------
// out[N x 128] = epilogue( A @ W ), A = [A1] (K=128) or [A1 ; A2] / [A1 ; Rg*A2] (K=256)
// M_SCALE: out = (A1@W) * dinv[row]
// M_GATE : out = sigmoid([A1;A2]@W + bias)
// M_CAND : pre = [A1; Rg*A2]@W + bias; out = (1-U)*A2 + U*tanh(pre)   (in-place ok)
// M_OUT  : out = A1@W + bias
template<int MODE, int K>
__global__ __launch_bounds__(256) void mm_kernel(
    const float* __restrict__ A1, const float* __restrict__ A2,
    const float* __restrict__ Rg, const float* __restrict__ W,
    const float* __restrict__ bias, const float* __restrict__ dinv,
    const float* __restrict__ U, float* __restrict__ out)
{
  __shared__ float At[BK][BM+4];   // transposed A tile, stride 36 (16B-aligned, bank-spread)
  __shared__ float Wt[BK][BN];
  const int tid = threadIdx.x;
  const int bm0 = blockIdx.x * BM;
  const int r0 = (tid >> 5) * 4;      // 8 row groups x 4 rows
  const int c0 = (tid & 31) * 4;      // 32 col groups x 4 cols
  float acc[4][4];
  #pragma unroll
  for (int i=0;i<4;i++)
    #pragma unroll
    for (int j=0;j<4;j++) acc[i][j]=0.f;

  const int a_row = tid >> 3;         // 0..31
  const int a_kc  = (tid & 7) * 4;    // 0,4,...,28
  const int w_r   = tid >> 5;         // 0..7
  const int w_c   = (tid & 31) * 4;
  const int grow  = bm0 + a_row;

  for (int kt=0; kt<K/BK; ++kt){
    const int kbase = kt*BK;
    // stage A (transposed into LDS)
    float4 av = make_float4(0.f,0.f,0.f,0.f);
    if (grow < NN){
      int gk = kbase + a_kc;
      if (K==256 && gk >= 128){
        int g2 = gk - 128;
        av = *(const float4*)(A2 + (size_t)grow*HH + g2);
        if constexpr (MODE==M_CAND){
          float4 rv = *(const float4*)(Rg + (size_t)grow*HH + g2);
          av.x*=rv.x; av.y*=rv.y; av.z*=rv.z; av.w*=rv.w;
        }
      } else {
        av = *(const float4*)(A1 + (size_t)grow*HH + gk);
      }
    }
    At[a_kc+0][a_row]=av.x;
    At[a_kc+1][a_row]=av.y;
    At[a_kc+2][a_row]=av.z;
    At[a_kc+3][a_row]=av.w;
    // stage W
    #pragma unroll
    for (int i=0;i<4;i++){
      int wr = w_r + 8*i;
      *(float4*)&Wt[wr][w_c] = *(const float4*)(W + (size_t)(kbase+wr)*BN + w_c);
    }
    __syncthreads();
    #pragma unroll
    for (int k=0;k<BK;k++){
      float4 a4 = *(const float4*)&At[k][r0];
      float4 w4 = *(const float4*)&Wt[k][c0];
      float aa[4]={a4.x,a4.y,a4.z,a4.w};
      float ww[4]={w4.x,w4.y,w4.z,w4.w};
      #pragma unroll
      for (int i=0;i<4;i++)
        #pragma unroll
        for (int j=0;j<4;j++) acc[i][j] += aa[i]*ww[j];
    }
    __syncthreads();
  }

  // epilogue
  float bs[4] = {0.f,0.f,0.f,0.f};
  if constexpr (MODE != M_SCALE){
    float4 bb = *(const float4*)(bias + c0);
    bs[0]=bb.x; bs[1]=bb.y; bs[2]=bb.z; bs[3]=bb.w;
  }
  #pragma unroll
  for (int i=0;i<4;i++){
    int row = bm0 + r0 + i;
    if (row >= NN) break;
    float o[4];
    if constexpr (MODE==M_SCALE){
      float d = dinv[row];
      #pragma unroll
      for (int j=0;j<4;j++) o[j] = acc[i][j]*d;
    } else if constexpr (MODE==M_GATE){
      #pragma unroll
      for (int j=0;j<4;j++) o[j] = sigmoidf_(acc[i][j]+bs[j]);
    } else if constexpr (MODE==M_CAND){
      float4 uu = *(const float4*)(U  + (size_t)row*HH + c0);
      float4 hp = *(const float4*)(A2 + (size_t)row*HH + c0);
      float u_[4]={uu.x,uu.y,uu.z,uu.w};
      float h_[4]={hp.x,hp.y,hp.z,hp.w};
      #pragma unroll
      for (int j=0;j<4;j++){
        float cd = tanhf(acc[i][j]+bs[j]);
        o[j] = (1.f-u_[j])*h_[j] + u_[j]*cd;
      }
    } else {
      #pragma unroll
      for (int j=0;j<4;j++) o[j] = acc[i][j]+bs[j];
    }
    *(float4*)(out + (size_t)row*HH + c0) = make_float4(o[0],o[1],o[2],o[3]);
  }
}

// ---------------- driver ----------------

extern "C" void kernel_launch(void* const* d_in, const int* in_sizes, int n_in,
                              void* d_out, int out_size, void* d_ws, size_t ws_size,
                              hipStream_t stream)
{
  const float* x_seq = (const float*)d_in[0];
  const int*   eidx  = (const int*)  d_in[1];
  const float* W_in0=(const float*)d_in[2];
  const float* b_in0=(const float*)d_in[3];
  const float* W_h0 =(const float*)d_in[4];
  const float* b_h0 =(const float*)d_in[5];
  const float* Wu0  =(const float*)d_in[6];
  const float* bu0  =(const float*)d_in[7];
  const float* Wr0  =(const float*)d_in[8];
  const float* br0  =(const float*)d_in[9];
  const float* Wc0  =(const float*)d_in[10];
  const float* bc0  =(const float*)d_in[11];
  const float* W_in1=(const float*)d_in[12];
  const float* b_in1=(const float*)d_in[13];
  const float* W_h1 =(const float*)d_in[14];
  const float* b_h1 =(const float*)d_in[15];
  const float* Wu1  =(const float*)d_in[16];
  const float* bu1  =(const float*)d_in[17];
  const float* Wr1  =(const float*)d_in[18];
  const float* br1  =(const float*)d_in[19];
  const float* Wc1  =(const float*)d_in[20];
  const float* bc1  =(const float*)d_in[21];
  const float* W_out=(const float*)d_in[22];
  const float* b_out=(const float*)d_in[23];
  float* out = (float*)d_out;

  char* p = (char*)d_ws;
  auto take = [&](size_t bytes)->void*{
    void* r = (void*)p;
    p += ((bytes + 255) & ~((size_t)255));
    return r;
  };
  const size_t fmat = (size_t)NN*HH*sizeof(float);
  float* h0   = (float*)take(fmat);
  float* h1   = (float*)take(fmat);
  float* T1   = (float*)take(fmat);
  float* T2   = (float*)take(fmat);
  float* Rb   = (float*)take(fmat);
  int*   counts=(int*)take((size_t)NN*4);
  int*   cursor=(int*)take((size_t)NN*4);
  int*   offs  =(int*)take((size_t)(NN+1)*4);
  int*   csr   =(int*)take((size_t)EE*4);
  float* dinv  =(float*)take((size_t)NN*4);

  hipMemsetAsync(h0, 0, fmat, stream);
  hipMemsetAsync(h1, 0, fmat, stream);

  dim3 mmG((NN+BM-1)/BM), mmB(256);
  dim3 agG((NN+7)/8), agB(256);
  dim3 eG((EE+255)/256), eB(256);

  for (int t=0; t<TT; ++t){
    const int* src = eidx + (size_t)t*2*EE;
    const int* dst = src + EE;
    const float* xt = x_seq + (size_t)t*NN*HH;
    float* outt = out + (size_t)t*NN*HH;

    hipMemsetAsync(counts, 0, (size_t)NN*4, stream);
    hipMemsetAsync(cursor, 0, (size_t)NN*4, stream);
    count_kernel<<<eG,eB,0,stream>>>(dst, counts);
    scan_kernel<<<1,1024,0,stream>>>(counts, offs, dinv);
    fill_kernel<<<eG,eB,0,stream>>>(src, dst, offs, cursor, csr);

    // ---- layer 0 cell (input xt, state h0) ----
    mm_kernel<M_SCALE,128><<<mmG,mmB,0,stream>>>(xt, nullptr, nullptr, W_in0, nullptr, dinv, nullptr, T1);
    agg_kernel<1><<<agG,agB,0,stream>>>(T1, csr, offs, dinv, b_in0, T2);
    mm_kernel<M_SCALE,128><<<mmG,mmB,0,stream>>>(T2, nullptr, nullptr, W_h0, nullptr, dinv, nullptr, T1);
    agg_kernel<0><<<agG,agB,0,stream>>>(T1, csr, offs, dinv, b_h0, T2);
    mm_kernel<M_GATE,256><<<mmG,mmB,0,stream>>>(T2, h0, nullptr, Wu0, bu0, nullptr, nullptr, T1); // u
    mm_kernel<M_GATE,256><<<mmG,mmB,0,stream>>>(T2, h0, nullptr, Wr0, br0, nullptr, nullptr, Rb); // r
    mm_kernel<M_CAND,256><<<mmG,mmB,0,stream>>>(T2, h0, Rb, Wc0, bc0, nullptr, T1, h0);           // h0 update

    // ---- layer 1 cell (input h0, state h1) ----
    mm_kernel<M_SCALE,128><<<mmG,mmB,0,stream>>>(h0, nullptr, nullptr, W_in1, nullptr, dinv, nullptr, T1);
    agg_kernel<1><<<agG,agB,0,stream>>>(T1, csr, offs, dinv, b_in1, T2);
    mm_kernel<M_SCALE,128><<<mmG,mmB,0,stream>>>(T2, nullptr, nullptr, W_h1, nullptr, dinv, nullptr, T1);
    agg_kernel<0><<<agG,agB,0,stream>>>(T1, csr, offs, dinv, b_h1, T2);
    mm_kernel<M_GATE,256><<<mmG,mmB,0,stream>>>(T2, h1, nullptr, Wu1, bu1, nullptr, nullptr, T1); // u
    mm_kernel<M_GATE,256><<<mmG,mmB,0,stream>>>(T2, h1, nullptr, Wr1, br1, nullptr, nullptr, Rb); // r
    mm_kernel<M_CAND,256><<<mmG,mmB,0,stream>>>(T2, h1, Rb, Wc1, bc1, nullptr, T1, h1);           // h1 update

    // ---- output projection ----
    mm_kernel<M_OUT,128><<<mmG,mmB,0,stream>>>(h1, nullptr, nullptr, W_out, b_out, nullptr, nullptr, outt);
  }
}

// Round 5
// 6032.623 us; speedup vs baseline: 1.2639x; 1.2639x over previous
//
#include <hip/hip_runtime.h>
#include <math.h>

#define TT 8
#define NN 50000
#define HH 128
#define EE 800000

#define M_SCALE 0
#define M_GATE  1
#define M_CAND  2
#define M_OUT   3

typedef __attribute__((ext_vector_type(8))) short short8;
typedef __attribute__((ext_vector_type(4))) float f32x4;

__device__ __forceinline__ float sigmoidf_(float x){ return 1.0f/(1.0f+__expf(-x)); }

// f32 -> bf16 (RTNE), and back
__device__ __forceinline__ short f2bf(float f){
  unsigned u = __float_as_uint(f);
  u += 0x7fff + ((u>>16)&1);
  return (short)(u>>16);
}
__device__ __forceinline__ float bf2f(short h){
  return __uint_as_float(((unsigned)(unsigned short)h)<<16);
}

// ---------------- CSR build ----------------

__global__ void count_kernel(const int* __restrict__ dst, int* __restrict__ counts){
  int e = blockIdx.x*256 + threadIdx.x;
  if (e < EE) atomicAdd(&counts[dst[e]], 1);
}

__global__ void scan_kernel(const int* __restrict__ counts, int* __restrict__ offs,
                            float* __restrict__ dinv){
  __shared__ int part[1024];
  const int t = threadIdx.x;
  const int per = (NN + 1023)/1024;
  int beg = t*per; int end = beg+per;
  if (end > NN) end = NN;
  if (beg > NN) beg = NN;
  int s = 0;
  for (int i=beg;i<end;i++) s += counts[i];
  part[t] = s; __syncthreads();
  for (int d=1; d<1024; d<<=1){
    int v = (t>=d) ? part[t-d] : 0;
    __syncthreads();
    part[t] += v;
    __syncthreads();
  }
  int run = part[t] - s;
  for (int i=beg;i<end;i++){
    offs[i] = run;
    int c = counts[i];
    run += c;
    dinv[i] = rsqrtf((float)c + 1.0f);
  }
  if (t==1023) offs[NN] = run;
}

__global__ void fill_kernel(const int* __restrict__ src, const int* __restrict__ dst,
                            const int* __restrict__ offs, int* __restrict__ cursor,
                            int* __restrict__ csr){
  int e = blockIdx.x*256 + threadIdx.x;
  if (e < EE){
    int d = dst[e];
    int p = atomicAdd(&cursor[d], 1);
    csr[offs[d]+p] = src[e];
  }
}

// ---------------- weight pre-split: W[K][128] f32 -> WT_hi/WT_lo[c][K] bf16 ----------------

__global__ void split_kernel(const float* __restrict__ W, short* __restrict__ WT_hi,
                             short* __restrict__ WT_lo, int K){
  int idx = blockIdx.x*256 + threadIdx.x;
  if (idx >= K*128) return;
  int c = idx & 127, k = idx >> 7;
  float v = W[k*128 + c];
  short h = f2bf(v);
  short l = f2bf(v - bf2f(h));
  WT_hi[(size_t)c*K + k] = h;
  WT_lo[(size_t)c*K + k] = l;
}

// ---------------- GCN aggregation ----------------
template<int RELU>
__global__ __launch_bounds__(256) void agg_kernel(
    const float* __restrict__ Ys, const int* __restrict__ csr,
    const int* __restrict__ offs, const float* __restrict__ dinv,
    const float* __restrict__ bias, float* __restrict__ out)
{
  const int node = blockIdx.x*8 + (threadIdx.x>>5);
  if (node >= NN) return;
  const int lane = threadIdx.x & 31;
  const float4* Y4 = (const float4*)Ys;
  float4 a = Y4[(size_t)node*32 + lane];
  float acc0=a.x, acc1=a.y, acc2=a.z, acc3=a.w;
  const int b = offs[node], e = offs[node+1];
  for (int j=b;j<e;j++){
    int s = csr[j];
    float4 v = Y4[(size_t)s*32 + lane];
    acc0+=v.x; acc1+=v.y; acc2+=v.z; acc3+=v.w;
  }
  const float d = dinv[node];
  const float4 bb = *(const float4*)(bias + lane*4);
  float o0 = acc0*d + bb.x;
  float o1 = acc1*d + bb.y;
  float o2 = acc2*d + bb.z;
  float o3 = acc3*d + bb.w;
  if (RELU){ o0=fmaxf(o0,0.f); o1=fmaxf(o1,0.f); o2=fmaxf(o2,0.f); o3=fmaxf(o3,0.f); }
  *(float4*)(out + (size_t)node*HH + lane*4) = make_float4(o0,o1,o2,o3);
}

// ---------------- MFMA GEMM (split-bf16, 3-product) ----------------
// out[N x 128] = epilogue( A @ W ), A = [A1] (K=128) or [A1 ; A2] / [A1 ; Rg*A2] (K=256)
// Block tile 128x128, 4 waves (each 64x64), K-chunk 64, XOR-swizzled LDS.
template<int MODE, int K>
__global__ __launch_bounds__(256,2) void mm_mfma(
    const float* __restrict__ A1, const float* __restrict__ A2,
    const float* __restrict__ Rg,
    const short* __restrict__ WT_hi, const short* __restrict__ WT_lo,
    const float* __restrict__ bias, const float* __restrict__ dinv,
    const float* __restrict__ U, float* __restrict__ out)
{
  __shared__ __align__(16) short Ah[128*64];
  __shared__ __align__(16) short Al[128*64];
  __shared__ __align__(16) short Bh[128*64];
  __shared__ __align__(16) short Bl[128*64];

  const int tid  = threadIdx.x;
  const int lane = tid & 63;
  const int w    = tid >> 6;
  const int bm0  = blockIdx.x * 128;
  const int row_w = (w>>1)*64, col_w = (w&1)*64;
  const int l15 = lane & 15, l4 = lane >> 4;

  f32x4 acc[4][4];
  #pragma unroll
  for (int mt=0;mt<4;mt++)
    #pragma unroll
    for (int nt=0;nt<4;nt++) acc[mt][nt] = (f32x4)(0.0f);

  const int srow  = tid >> 1;         // 0..127 (A-row / B-col this thread stages)
  const int shalf = (tid & 1) * 32;   // k-offset (elements) within the 64-wide chunk
  const int grow  = bm0 + srow;
  const unsigned skey = (unsigned)(srow & 7) << 4;

  for (int kc = 0; kc < K/64; ++kc){
    // ---- stage A: load f32, split to hi/lo bf16, swizzled ds_write ----
    const bool fromA2 = (K==256) && (kc >= 2);
    const float* asrc = fromA2 ? A2 : A1;
    const int koff = fromA2 ? (kc-2)*64 : kc*64;
    float av[32];
    if (grow < NN){
      const float* ap = asrc + (size_t)grow*HH + koff + shalf;
      #pragma unroll
      for (int j=0;j<8;j++) *(float4*)&av[j*4] = *(const float4*)(ap + j*4);
      if constexpr (MODE==M_CAND){
        if (fromA2){
          const float* rp = Rg + (size_t)grow*HH + koff + shalf;
          #pragma unroll
          for (int j=0;j<8;j++){
            float4 rv = *(const float4*)(rp + j*4);
            av[j*4+0]*=rv.x; av[j*4+1]*=rv.y; av[j*4+2]*=rv.z; av[j*4+3]*=rv.w;
          }
        }
      }
    } else {
      #pragma unroll
      for (int j=0;j<32;j++) av[j] = 0.f;
    }
    #pragma unroll
    for (int g=0; g<4; g++){
      short8 vh, vl;
      #pragma unroll
      for (int e=0;e<8;e++){
        float f = av[g*8+e];
        short h = f2bf(f);
        vh[e] = h;
        vl[e] = f2bf(f - bf2f(h));
      }
      unsigned byte = ((unsigned)(shalf*2 + g*16)) ^ skey;
      int idx = srow*64 + (int)(byte>>1);
      *(short8*)&Ah[idx] = vh;
      *(short8*)&Al[idx] = vl;
    }
    // ---- stage B: copy pre-split WT (bf16), swizzled ds_write ----
    {
      const short* sh = WT_hi + (size_t)srow*K + kc*64 + shalf;
      const short* sl = WT_lo + (size_t)srow*K + kc*64 + shalf;
      #pragma unroll
      for (int g=0; g<4; g++){
        short8 vh = *(const short8*)(sh + g*8);
        short8 vl = *(const short8*)(sl + g*8);
        unsigned byte = ((unsigned)(shalf*2 + g*16)) ^ skey;
        int idx = srow*64 + (int)(byte>>1);
        *(short8*)&Bh[idx] = vh;
        *(short8*)&Bl[idx] = vl;
      }
    }
    __syncthreads();
    // ---- compute: 2 k-slices of 32, 16 fragments, 3 MFMAs each ----
    #pragma unroll
    for (int kk=0; kk<2; kk++){
      short8 ahf[4], alf[4], bhf[4], blf[4];
      #pragma unroll
      for (int mt=0; mt<4; mt++){
        int r = row_w + mt*16 + l15;
        unsigned byte = ((unsigned)(kk*64 + l4*16)) ^ ((unsigned)(r&7)<<4);
        int idx = r*64 + (int)(byte>>1);
        ahf[mt] = *(const short8*)&Ah[idx];
        alf[mt] = *(const short8*)&Al[idx];
      }
      #pragma unroll
      for (int nt=0; nt<4; nt++){
        int c = col_w + nt*16 + l15;
        unsigned byte = ((unsigned)(kk*64 + l4*16)) ^ ((unsigned)(c&7)<<4);
        int idx = c*64 + (int)(byte>>1);
        bhf[nt] = *(const short8*)&Bh[idx];
        blf[nt] = *(const short8*)&Bl[idx];
      }
      #pragma unroll
      for (int mt=0; mt<4; mt++)
        #pragma unroll
        for (int nt=0; nt<4; nt++){
          acc[mt][nt] = __builtin_amdgcn_mfma_f32_16x16x32_bf16(ahf[mt], bhf[nt], acc[mt][nt], 0,0,0);
          acc[mt][nt] = __builtin_amdgcn_mfma_f32_16x16x32_bf16(ahf[mt], blf[nt], acc[mt][nt], 0,0,0);
          acc[mt][nt] = __builtin_amdgcn_mfma_f32_16x16x32_bf16(alf[mt], bhf[nt], acc[mt][nt], 0,0,0);
        }
    }
    __syncthreads();
  }

  // ---- epilogue ----
  float bs[4] = {0.f,0.f,0.f,0.f};
  if constexpr (MODE != M_SCALE){
    #pragma unroll
    for (int nt=0;nt<4;nt++) bs[nt] = bias[col_w + nt*16 + l15];
  }
  #pragma unroll
  for (int mt=0; mt<4; mt++){
    #pragma unroll
    for (int r=0; r<4; r++){
      int row = bm0 + row_w + mt*16 + l4*4 + r;
      if (row < NN){
        float dv = 0.f;
        if constexpr (MODE==M_SCALE) dv = dinv[row];
        #pragma unroll
        for (int nt=0; nt<4; nt++){
          int col = col_w + nt*16 + l15;
          float v = acc[mt][nt][r];
          if constexpr (MODE==M_SCALE){
            v *= dv;
          } else if constexpr (MODE==M_GATE){
            v = sigmoidf_(v + bs[nt]);
          } else if constexpr (MODE==M_CAND){
            size_t ix = (size_t)row*HH + col;
            float u = U[ix], hp = A2[ix];
            v = (1.f-u)*hp + u*tanhf(v + bs[nt]);
          } else {
            v += bs[nt];
          }
          out[(size_t)row*HH + col] = v;
        }
      }
    }
  }
}

// ---------------- driver ----------------

extern "C" void kernel_launch(void* const* d_in, const int* in_sizes, int n_in,
                              void* d_out, int out_size, void* d_ws, size_t ws_size,
                              hipStream_t stream)
{
  const float* x_seq = (const float*)d_in[0];
  const int*   eidx  = (const int*)  d_in[1];
  const float* W_in0=(const float*)d_in[2];
  const float* b_in0=(const float*)d_in[3];
  const float* W_h0 =(const float*)d_in[4];
  const float* b_h0 =(const float*)d_in[5];
  const float* Wu0  =(const float*)d_in[6];
  const float* bu0  =(const float*)d_in[7];
  const float* Wr0  =(const float*)d_in[8];
  const float* br0  =(const float*)d_in[9];
  const float* Wc0  =(const float*)d_in[10];
  const float* bc0  =(const float*)d_in[11];
  const float* W_in1=(const float*)d_in[12];
  const float* b_in1=(const float*)d_in[13];
  const float* W_h1 =(const float*)d_in[14];
  const float* b_h1 =(const float*)d_in[15];
  const float* Wu1  =(const float*)d_in[16];
  const float* bu1  =(const float*)d_in[17];
  const float* Wr1  =(const float*)d_in[18];
  const float* br1  =(const float*)d_in[19];
  const float* Wc1  =(const float*)d_in[20];
  const float* bc1  =(const float*)d_in[21];
  const float* W_out=(const float*)d_in[22];
  const float* b_out=(const float*)d_in[23];
  float* out = (float*)d_out;

  char* p = (char*)d_ws;
  auto take = [&](size_t bytes)->void*{
    void* r = (void*)p;
    p += ((bytes + 255) & ~((size_t)255));
    return r;
  };
  const size_t fmat = (size_t)NN*HH*sizeof(float);
  float* h0   = (float*)take(fmat);
  float* h1   = (float*)take(fmat);
  float* T1   = (float*)take(fmat);
  float* T2   = (float*)take(fmat);
  float* Rb   = (float*)take(fmat);
  int*   counts=(int*)take((size_t)NN*4);
  int*   cursor=(int*)take((size_t)NN*4);
  int*   offs  =(int*)take((size_t)(NN+1)*4);
  int*   csr   =(int*)take((size_t)EE*4);
  float* dinv  =(float*)take((size_t)NN*4);

  // pre-split weight storage (bf16 hi/lo, transposed [c][K])
  const float* Wsrc[11] = {W_in0, W_h0, Wu0, Wr0, Wc0, W_in1, W_h1, Wu1, Wr1, Wc1, W_out};
  const int    Wk[11]   = {128,   128,  256, 256, 256, 128,   128,  256, 256, 256, 128};
  short* Wh[11]; short* Wl[11];
  for (int i=0;i<11;i++){
    Wh[i] = (short*)take((size_t)Wk[i]*128*2);
    Wl[i] = (short*)take((size_t)Wk[i]*128*2);
  }

  hipMemsetAsync(h0, 0, fmat, stream);
  hipMemsetAsync(h1, 0, fmat, stream);

  for (int i=0;i<11;i++)
    split_kernel<<<(Wk[i]*128+255)/256, 256, 0, stream>>>(Wsrc[i], Wh[i], Wl[i], Wk[i]);

  dim3 mmG((NN+127)/128), mmB(256);
  dim3 agG((NN+7)/8), agB(256);
  dim3 eG((EE+255)/256), eB(256);

  for (int t=0; t<TT; ++t){
    const int* src = eidx + (size_t)t*2*EE;
    const int* dst = src + EE;
    const float* xt = x_seq + (size_t)t*NN*HH;
    float* outt = out + (size_t)t*NN*HH;

    hipMemsetAsync(counts, 0, (size_t)NN*4, stream);
    hipMemsetAsync(cursor, 0, (size_t)NN*4, stream);
    count_kernel<<<eG,eB,0,stream>>>(dst, counts);
    scan_kernel<<<1,1024,0,stream>>>(counts, offs, dinv);
    fill_kernel<<<eG,eB,0,stream>>>(src, dst, offs, cursor, csr);

    // ---- layer 0 cell (input xt, state h0) ----
    mm_mfma<M_SCALE,128><<<mmG,mmB,0,stream>>>(xt, nullptr, nullptr, Wh[0],Wl[0], nullptr, dinv, nullptr, T1);
    agg_kernel<1><<<agG,agB,0,stream>>>(T1, csr, offs, dinv, b_in0, T2);
    mm_mfma<M_SCALE,128><<<mmG,mmB,0,stream>>>(T2, nullptr, nullptr, Wh[1],Wl[1], nullptr, dinv, nullptr, T1);
    agg_kernel<0><<<agG,agB,0,stream>>>(T1, csr, offs, dinv, b_h0, T2);
    mm_mfma<M_GATE,256><<<mmG,mmB,0,stream>>>(T2, h0, nullptr, Wh[2],Wl[2], bu0, nullptr, nullptr, T1); // u
    mm_mfma<M_GATE,256><<<mmG,mmB,0,stream>>>(T2, h0, nullptr, Wh[3],Wl[3], br0, nullptr, nullptr, Rb); // r
    mm_mfma<M_CAND,256><<<mmG,mmB,0,stream>>>(T2, h0, Rb, Wh[4],Wl[4], bc0, nullptr, T1, h0);           // h0

    // ---- layer 1 cell (input h0, state h1) ----
    mm_mfma<M_SCALE,128><<<mmG,mmB,0,stream>>>(h0, nullptr, nullptr, Wh[5],Wl[5], nullptr, dinv, nullptr, T1);
    agg_kernel<1><<<agG,agB,0,stream>>>(T1, csr, offs, dinv, b_in1, T2);
    mm_mfma<M_SCALE,128><<<mmG,mmB,0,stream>>>(T2, nullptr, nullptr, Wh[6],Wl[6], nullptr, dinv, nullptr, T1);
    agg_kernel<0><<<agG,agB,0,stream>>>(T1, csr, offs, dinv, b_h1, T2);
    mm_mfma<M_GATE,256><<<mmG,mmB,0,stream>>>(T2, h1, nullptr, Wh[7],Wl[7], bu1, nullptr, nullptr, T1); // u
    mm_mfma<M_GATE,256><<<mmG,mmB,0,stream>>>(T2, h1, nullptr, Wh[8],Wl[8], br1, nullptr, nullptr, Rb); // r
    mm_mfma<M_CAND,256><<<mmG,mmB,0,stream>>>(T2, h1, Rb, Wh[9],Wl[9], bc1, nullptr, T1, h1);           // h1

    // ---- output projection ----
    mm_mfma<M_OUT,128><<<mmG,mmB,0,stream>>>(h1, nullptr, nullptr, Wh[10],Wl[10], b_out, nullptr, nullptr, outt);
  }
}